// Round 1
// baseline (18770.055 us; speedup 1.0000x reference)
//
#include <hip/hip_runtime.h>
#include <hip/hip_bf16.h>

#define S_LEN 2048
#define NB    32
#define NK    512     // IN_DIM == HID == 512
#define NH    512
#define N4H   2048
#define NWG   64
#define JPW   8       // hidden columns per WG

typedef __attribute__((ext_vector_type(8)))  short  short8;
typedef __attribute__((ext_vector_type(4)))  float  floatx4;
typedef __attribute__((ext_vector_type(16))) float  floatx16;

__device__ __forceinline__ short f2bf(float f) {
  union { float f; unsigned u; } v; v.f = f;
  unsigned r = v.u + 0x7fffu + ((v.u >> 16) & 1u);
  return (short)(r >> 16);
}

__device__ __forceinline__ float sigm(float x) { return 1.f / (1.f + __expf(-x)); }

__global__ __launch_bounds__(256, 1) void plstm_persist(
    const float* __restrict__ X,  const float* __restrict__ Wx, const float* __restrict__ bx,
    const float* __restrict__ Wh, const float* __restrict__ bh, const float* __restrict__ zc,
    float* __restrict__ out, unsigned* __restrict__ flags,
    unsigned long long* __restrict__ hbuf)   // 2 x 4096 ulongs (32x512 bf16 each)
{
  const int tid  = threadIdx.x;
  const int g    = blockIdx.x;
  const int wv   = tid >> 6;
  const int lane = tid & 63;
  const int jbase = g * JPW;

  const int colN  = lane & 31;        // n_local = q*8+jj
  const int kgrp  = lane >> 5;
  const int qgate = colN >> 3;
  const int jj    = colN & 7;
  const int nglob = qgate * NH + jbase + jj;
  const int arow  = lane & 31;        // batch row for A frags

  // B-fragments (weights) resident in registers for this wave's K-quarter
  short8 wxr[8], whr[8];
  #pragma unroll
  for (int it = 0; it < 8; ++it) {
    const int k0 = wv * 128 + it * 16 + kgrp * 8;
    short8 a, b;
    #pragma unroll
    for (int e = 0; e < 8; ++e) {
      a[e] = f2bf(Wx[(size_t)(k0 + e) * N4H + nglob]);
      b[e] = f2bf(Wh[(size_t)(k0 + e) * N4H + nglob]);
    }
    wxr[it] = a; whr[it] = b;
  }

  // per-thread elementwise ownership: (batch m_own, hidden jbase+j_own)
  const int m_own = tid >> 3;   // 0..31
  const int j_own = tid & 7;    // 0..7
  float bsum[4];
  #pragma unroll
  for (int q = 0; q < 4; ++q)
    bsum[q] = bx[q * NH + jbase + j_own] + bh[q * NH + jbase + j_own];
  const float zcv = zc[jbase + j_own];
  float cstate = 0.f;

  __shared__ float lds_acc[4][32][33];
  __shared__ unsigned short lds_hs[32][8];

  for (int t = 0; t < S_LEN; ++t) {
    floatx16 acc;
    #pragma unroll
    for (int r = 0; r < 16; ++r) acc[r] = 0.f;

    // ---- input projection gx = X[t] @ Wx (no sequential dependency) ----
    const float* Xt = X + (size_t)t * NB * NK;
    #pragma unroll
    for (int it = 0; it < 8; ++it) {
      const int k0 = wv * 128 + it * 16 + kgrp * 8;
      const floatx4* p = (const floatx4*)(Xt + arow * NK + k0);
      floatx4 x0 = p[0], x1 = p[1];
      short8 af;
      #pragma unroll
      for (int e = 0; e < 4; ++e) { af[e] = f2bf(x0[e]); af[4 + e] = f2bf(x1[e]); }
      acc = __builtin_amdgcn_mfma_f32_32x32x16_bf16(af, wxr[it], acc, 0, 0, 0);
    }

    // ---- recurrent part: h_{t-1} @ Wh ----
    if (t > 0) {
      if (tid < NWG) {
        while (__hip_atomic_load(&flags[tid * 16], __ATOMIC_ACQUIRE,
                                 __HIP_MEMORY_SCOPE_AGENT) < (unsigned)t)
          __builtin_amdgcn_s_sleep(1);
      }
      __syncthreads();
      const unsigned* hb = (const unsigned*)(hbuf + ((size_t)((t - 1) & 1)) * 4096);
      #pragma unroll
      for (int it = 0; it < 8; ++it) {
        const int k0 = wv * 128 + it * 16 + kgrp * 8;
        const unsigned* hp = hb + ((arow * NH + k0) >> 1);
        unsigned u0 = __hip_atomic_load(hp + 0, __ATOMIC_RELAXED, __HIP_MEMORY_SCOPE_AGENT);
        unsigned u1 = __hip_atomic_load(hp + 1, __ATOMIC_RELAXED, __HIP_MEMORY_SCOPE_AGENT);
        unsigned u2 = __hip_atomic_load(hp + 2, __ATOMIC_RELAXED, __HIP_MEMORY_SCOPE_AGENT);
        unsigned u3 = __hip_atomic_load(hp + 3, __ATOMIC_RELAXED, __HIP_MEMORY_SCOPE_AGENT);
        short8 af;
        af[0] = (short)(u0 & 0xffffu); af[1] = (short)(u0 >> 16);
        af[2] = (short)(u1 & 0xffffu); af[3] = (short)(u1 >> 16);
        af[4] = (short)(u2 & 0xffffu); af[5] = (short)(u2 >> 16);
        af[6] = (short)(u3 & 0xffffu); af[7] = (short)(u3 >> 16);
        acc = __builtin_amdgcn_mfma_f32_32x32x16_bf16(af, whr[it], acc, 0, 0, 0);
      }
    }

    // ---- cross-wave partial reduction via LDS ----
    #pragma unroll
    for (int r = 0; r < 16; ++r) {
      const int row = (r & 3) + 8 * (r >> 2) + 4 * kgrp;   // verified 32x32 C/D layout
      lds_acc[wv][row][colN] = acc[r];
    }
    __syncthreads();

    float pre[4];
    #pragma unroll
    for (int q = 0; q < 4; ++q) {
      const int cc = q * 8 + j_own;
      pre[q] = lds_acc[0][m_own][cc] + lds_acc[1][m_own][cc]
             + lds_acc[2][m_own][cc] + lds_acc[3][m_own][cc] + bsum[q];
    }
    const float iv = sigm(pre[0]);
    const float ov = sigm(pre[1]);
    const float fv = sigm(pre[3]);
    const float zv = tanhf(pre[2] + zcv * cstate);   // peephole on block input
    cstate = iv * zv + fv * cstate;
    const float hv = ov * tanhf(cstate);

    out[((size_t)t * NB + m_own) * NH + jbase + j_own] = hv;
    if (t == S_LEN - 1) {
      out[(size_t)S_LEN * NB * NH + (size_t)m_own * NH + jbase + j_own] = hv;
      out[(size_t)S_LEN * NB * NH + (size_t)NB * NH + (size_t)m_own * NH + jbase + j_own] = cstate;
    }

    // ---- publish h_t (bf16) for all WGs ----
    lds_hs[m_own][j_own] = (unsigned short)f2bf(hv);
    __syncthreads();

    if (tid < 64) {
      const int mm = tid >> 1, half = tid & 1;
      unsigned long long u = *(const unsigned long long*)&lds_hs[mm][half * 4];
      unsigned long long* hbo = hbuf + ((size_t)(t & 1)) * 4096;
      __hip_atomic_store(&hbo[mm * 128 + (jbase >> 2) + half], u,
                         __ATOMIC_RELAXED, __HIP_MEMORY_SCOPE_AGENT);
    }
    __syncthreads();   // drains vmcnt: all publishes complete before flag
    if (tid == 0)
      __hip_atomic_store(&flags[g * 16], (unsigned)(t + 1),
                         __ATOMIC_RELEASE, __HIP_MEMORY_SCOPE_AGENT);
  }
}

extern "C" void kernel_launch(void* const* d_in, const int* in_sizes, int n_in,
                              void* d_out, int out_size, void* d_ws, size_t ws_size,
                              hipStream_t stream) {
  const float* X  = (const float*)d_in[0];
  const float* Wx = (const float*)d_in[1];
  const float* bx = (const float*)d_in[2];
  const float* Wh = (const float*)d_in[3];
  const float* bh = (const float*)d_in[4];
  const float* zc = (const float*)d_in[5];
  float* out = (float*)d_out;
  unsigned* flags = (unsigned*)d_ws;                                   // 64 flags, 64B apart
  unsigned long long* hbuf = (unsigned long long*)((char*)d_ws + 4096); // 2 x 32KB bf16 h

  hipMemsetAsync(d_ws, 0, 4096, stream);  // flags must start at 0 every launch
  hipLaunchKernelGGL(plstm_persist, dim3(NWG), dim3(256), 0, stream,
                     X, Wx, bx, Wh, bh, zc, out, flags, hbuf);
}

// Round 2
// 11802.771 us; speedup vs baseline: 1.5903x; 1.5903x over previous
//
#include <hip/hip_runtime.h>
#include <hip/hip_bf16.h>

#define S_LEN 2048
#define NB    32
#define NK    512     // IN_DIM == HID == 512
#define NH    512
#define N4H   2048
#define NWG   64
#define JPW   8       // hidden columns per WG

typedef __attribute__((ext_vector_type(8)))  short  short8;
typedef __attribute__((ext_vector_type(4)))  float  floatx4;
typedef __attribute__((ext_vector_type(16))) float  floatx16;

__device__ __forceinline__ short f2bf(float f) {
  union { float f; unsigned u; } v; v.f = f;
  unsigned r = v.u + 0x7fffu + ((v.u >> 16) & 1u);
  return (short)(r >> 16);
}

__device__ __forceinline__ float sigm(float x) { return 1.f / (1.f + __expf(-x)); }

__global__ __launch_bounds__(256, 1) void plstm_persist(
    const float* __restrict__ X,  const float* __restrict__ Wx, const float* __restrict__ bx,
    const float* __restrict__ Wh, const float* __restrict__ bh, const float* __restrict__ zc,
    float* __restrict__ out, unsigned* __restrict__ flags,
    unsigned long long* __restrict__ hbuf)   // 2 x 4096 ulongs (32x512 bf16 each)
{
  const int tid  = threadIdx.x;
  const int g    = blockIdx.x;
  const int wv   = tid >> 6;
  const int lane = tid & 63;
  const int jbase = g * JPW;

  const int colN  = lane & 31;        // n_local = q*8+jj
  const int kgrp  = lane >> 5;
  const int qgate = colN >> 3;
  const int jj    = colN & 7;
  const int nglob = qgate * NH + jbase + jj;
  const int arow  = lane & 31;        // batch row for A frags

  // B-fragments (weights) resident in registers for this wave's K-quarter
  short8 wxr[8], whr[8];
  #pragma unroll
  for (int it = 0; it < 8; ++it) {
    const int k0 = wv * 128 + it * 16 + kgrp * 8;
    short8 a, b;
    #pragma unroll
    for (int e = 0; e < 8; ++e) {
      a[e] = f2bf(Wx[(size_t)(k0 + e) * N4H + nglob]);
      b[e] = f2bf(Wh[(size_t)(k0 + e) * N4H + nglob]);
    }
    wxr[it] = a; whr[it] = b;
  }

  // per-thread elementwise ownership: (batch m_own, hidden jbase+j_own)
  const int m_own = tid >> 3;   // 0..31
  const int j_own = tid & 7;    // 0..7
  float bsum[4];
  #pragma unroll
  for (int q = 0; q < 4; ++q)
    bsum[q] = bx[q * NH + jbase + j_own] + bh[q * NH + jbase + j_own];
  const float zcv = zc[jbase + j_own];
  float cstate = 0.f;

  __shared__ float lds_acc[4][32][36];      // pad 36: reduce-read is 2-way (free)
  __shared__ unsigned short lds_hs[32][8];

  // ---- prologue: X[0] fragments into registers ----
  short8 xf[8];
  {
    const floatx4* p0 = (const floatx4*)(X + arow * NK);
    #pragma unroll
    for (int it = 0; it < 8; ++it) {
      const int k0 = wv * 128 + it * 16 + kgrp * 8;
      floatx4 x0 = p0[k0 >> 2], x1 = p0[(k0 >> 2) + 1];
      short8 a;
      #pragma unroll
      for (int e = 0; e < 4; ++e) { a[e] = f2bf(x0[e]); a[4 + e] = f2bf(x1[e]); }
      xf[it] = a;
    }
  }

  for (int t = 0; t < S_LEN; ++t) {
    floatx16 acc;
    #pragma unroll
    for (int r = 0; r < 16; ++r) acc[r] = 0.f;

    // ---- wait for h_{t-1} from all WGs (relaxed poll: NO buffer_inv) ----
    if (t > 0) {
      if (tid < NWG) {
        const unsigned* f = &flags[tid * 16];
        while (__hip_atomic_load(f, __ATOMIC_RELAXED, __HIP_MEMORY_SCOPE_AGENT)
               < (unsigned)t) { }
      }
      __syncthreads();
    }

    // ---- issue h loads (coherent 8B atomics, bypass stale L1/L2) ----
    unsigned long long hv64[16];
    if (t > 0) {
      const unsigned long long* hb = hbuf + ((size_t)((t - 1) & 1)) * 4096;
      #pragma unroll
      for (int it = 0; it < 8; ++it) {
        const int k0 = wv * 128 + it * 16 + kgrp * 8;
        const unsigned long long* hp = hb + ((arow * NH + k0) >> 2);
        hv64[2 * it]     = __hip_atomic_load(hp,     __ATOMIC_RELAXED, __HIP_MEMORY_SCOPE_AGENT);
        hv64[2 * it + 1] = __hip_atomic_load(hp + 1, __ATOMIC_RELAXED, __HIP_MEMORY_SCOPE_AGENT);
      }
    }

    // ---- issue X[t+1] prefetch (completes during compute, off critical path) ----
    floatx4 xnew[16];
    if (t + 1 < S_LEN) {
      const floatx4* p = (const floatx4*)(X + (size_t)(t + 1) * NB * NK + arow * NK);
      #pragma unroll
      for (int it = 0; it < 8; ++it) {
        const int k0 = wv * 128 + it * 16 + kgrp * 8;
        xnew[2 * it]     = p[k0 >> 2];
        xnew[2 * it + 1] = p[(k0 >> 2) + 1];
      }
    }

    // ---- input-projection MFMAs: fragments already in registers ----
    #pragma unroll
    for (int it = 0; it < 8; ++it)
      acc = __builtin_amdgcn_mfma_f32_32x32x16_bf16(xf[it], wxr[it], acc, 0, 0, 0);

    // ---- recurrent MFMAs ----
    if (t > 0) {
      #pragma unroll
      for (int it = 0; it < 8; ++it) {
        const unsigned lo0 = (unsigned)hv64[2 * it];
        const unsigned hi0 = (unsigned)(hv64[2 * it] >> 32);
        const unsigned lo1 = (unsigned)hv64[2 * it + 1];
        const unsigned hi1 = (unsigned)(hv64[2 * it + 1] >> 32);
        short8 af;
        af[0] = (short)(lo0 & 0xffffu); af[1] = (short)(lo0 >> 16);
        af[2] = (short)(hi0 & 0xffffu); af[3] = (short)(hi0 >> 16);
        af[4] = (short)(lo1 & 0xffffu); af[5] = (short)(lo1 >> 16);
        af[6] = (short)(hi1 & 0xffffu); af[7] = (short)(hi1 >> 16);
        acc = __builtin_amdgcn_mfma_f32_32x32x16_bf16(af, whr[it], acc, 0, 0, 0);
      }
    }

    // ---- cross-wave partial reduction via LDS ----
    #pragma unroll
    for (int r = 0; r < 16; ++r) {
      const int row = (r & 3) + 8 * (r >> 2) + 4 * kgrp;   // verified 32x32 C/D layout
      lds_acc[wv][row][colN] = acc[r];
    }
    __syncthreads();

    float pre[4];
    #pragma unroll
    for (int q = 0; q < 4; ++q) {
      const int cc = q * 8 + j_own;
      pre[q] = lds_acc[0][m_own][cc] + lds_acc[1][m_own][cc]
             + lds_acc[2][m_own][cc] + lds_acc[3][m_own][cc] + bsum[q];
    }
    const float iv = sigm(pre[0]);
    const float ov = sigm(pre[1]);
    const float fv = sigm(pre[3]);
    const float zv = tanhf(pre[2] + zcv * cstate);   // peephole on block input
    cstate = iv * zv + fv * cstate;
    const float hv = ov * tanhf(cstate);

    out[((size_t)t * NB + m_own) * NH + jbase + j_own] = hv;
    if (t == S_LEN - 1) {
      out[(size_t)S_LEN * NB * NH + (size_t)m_own * NH + jbase + j_own] = hv;
      out[(size_t)S_LEN * NB * NH + (size_t)NB * NH + (size_t)m_own * NH + jbase + j_own] = cstate;
    }

    // ---- publish h_t (wave 0 only): stores -> vmcnt(0) -> flag, all relaxed ----
    lds_hs[m_own][j_own] = (unsigned short)f2bf(hv);
    __syncthreads();

    if (tid < 64) {
      const int mm = tid >> 1, half = tid & 1;
      unsigned long long u = *(const unsigned long long*)&lds_hs[mm][half * 4];
      unsigned long long* hbo = hbuf + ((size_t)(t & 1)) * 4096;
      __hip_atomic_store(&hbo[mm * 128 + (jbase >> 2) + half], u,
                         __ATOMIC_RELAXED, __HIP_MEMORY_SCOPE_AGENT);
      asm volatile("s_waitcnt vmcnt(0)" ::: "memory");   // h visible at LLC
      if (tid == 0)
        __hip_atomic_store(&flags[g * 16], (unsigned)(t + 1),
                           __ATOMIC_RELAXED, __HIP_MEMORY_SCOPE_AGENT);
    }

    // ---- convert X prefetch for next step (off the publish critical path) ----
    if (t + 1 < S_LEN) {
      #pragma unroll
      for (int it = 0; it < 8; ++it) {
        short8 a;
        #pragma unroll
        for (int e = 0; e < 4; ++e) {
          a[e]     = f2bf(xnew[2 * it][e]);
          a[4 + e] = f2bf(xnew[2 * it + 1][e]);
        }
        xf[it] = a;
      }
    }
  }
}

extern "C" void kernel_launch(void* const* d_in, const int* in_sizes, int n_in,
                              void* d_out, int out_size, void* d_ws, size_t ws_size,
                              hipStream_t stream) {
  const float* X  = (const float*)d_in[0];
  const float* Wx = (const float*)d_in[1];
  const float* bx = (const float*)d_in[2];
  const float* Wh = (const float*)d_in[3];
  const float* bh = (const float*)d_in[4];
  const float* zc = (const float*)d_in[5];
  float* out = (float*)d_out;
  unsigned* flags = (unsigned*)d_ws;                                   // 64 flags, 64B apart
  unsigned long long* hbuf = (unsigned long long*)((char*)d_ws + 4096); // 2 x 32KB bf16 h

  hipMemsetAsync(d_ws, 0, 4096, stream);  // flags must start at 0 every launch
  hipLaunchKernelGGL(plstm_persist, dim3(NWG), dim3(256), 0, stream,
                     X, Wx, bx, Wh, bh, zc, out, flags, hbuf);
}